// Round 1
// baseline (344.661 us; speedup 1.0000x reference)
//
#include <hip/hip_runtime.h>
#include <math.h>

#define NBANDS 2049
#define NF 4096      // real frame size
#define NC 2048      // complex FFT size (rfft via packed complex)
#define BUF 1024     // input samples per batch row
#define THREADS 512

struct Smem {
  float  xs[BUF];        // 4 KB
  float2 za[NC];         // 16 KB
  float2 zb[NC];         // 16 KB
  float  S0[NBANDS];     // 8.2 KB
  float  S1[NBANDS];
  float  S2[NBANDS];
};                       // total 61452 B (< 64 KB static)

// MODE: 0 -> S0[k] = min(p,1e6); 1 -> S1[k]=min(S0,p); 2 -> S2[k]=min(S1,p);
//       3 -> out[k*8] = dB(min(S2,p))
template <int MODE>
__device__ void frame_power(Smem& sm, int lvl, int off, float* outp) {
  const int tid = threadIdx.x;
  const int s = 1 << lvl;
  const int M = NF >> lvl;                 // window support length
  const int k0 = max(NF - off, NF - M);    // first nonzero sample of w*frame
  const float ws = (float)s * (0.5f / 1024.0f);
  const int xoff = NF - off;               // frame[k] = x[k - xoff] for k >= xoff

  // ---- build packed complex input: z[n] = wf(2n) + i*wf(2n+1) ----
  __syncthreads();   // previous unpack readers done with za/zb
  for (int n = tid; n < NC; n += THREADS) {
    float re = 0.0f, im = 0.0f;
    int k = 2 * n;
    if (k >= k0) {
      float c = cospif((float)(k * s) * (1.0f / 2048.0f));
      re = ws * (1.0f - c) * sm.xs[k - xoff];
    }
    k = 2 * n + 1;
    if (k >= k0) {
      float c = cospif((float)(k * s) * (1.0f / 2048.0f));
      im = ws * (1.0f - c) * sm.xs[k - xoff];
    }
    sm.za[n] = make_float2(re, im);
  }

  // ---- Stockham radix-2 FFT, 11 stages, ping-pong za<->zb ----
  float2* A = sm.za;
  float2* Bq = sm.zb;
  int n = NC;
  #pragma unroll 1
  for (int stage = 0; stage < 11; ++stage) {
    const int span = 1 << stage;
    const float rinv = 1.0f / (float)n;
    __syncthreads();
    for (int j = tid; j < NC / 2; j += THREADS) {
      const int p = j >> stage;
      const int q = j & (span - 1);
      float2 c0 = A[j];
      float2 c1 = A[j + NC / 2];
      float2 d0 = make_float2(c0.x + c1.x, c0.y + c1.y);
      float2 d1 = make_float2(c0.x - c1.x, c0.y - c1.y);
      float sn, cs;
      sincospif(-2.0f * (float)p * rinv, &sn, &cs);  // exp(-2*pi*i*p/n)
      float2 e = make_float2(cs * d1.x - sn * d1.y, cs * d1.y + sn * d1.x);
      const int base = 2 * j - q;
      Bq[base] = d0;
      Bq[base + span] = e;
    }
    { float2* t = A; A = Bq; Bq = t; }
    n >>= 1;
  }
  __syncthreads();

  // ---- unpack real-FFT bins + power + min-chain action ----
  for (int k = tid; k < NBANDS; k += THREADS) {
    const int k1 = k & (NC - 1);
    const int k2 = (NC - k) & (NC - 1);
    float2 Zk = A[k1];
    float2 Zm = A[k2];
    float2 Bc = make_float2(Zm.x, -Zm.y);           // conj(Z[N-k])
    float2 E = make_float2(0.5f * (Zk.x + Bc.x), 0.5f * (Zk.y + Bc.y));
    float2 O = make_float2(0.5f * (Zk.y - Bc.y), -0.5f * (Zk.x - Bc.x)); // -i/2*(Zk-Bc)
    float sn, cs;
    sincospif(-(float)k * (1.0f / 2048.0f), &sn, &cs); // exp(-2*pi*i*k/4096)
    float Fx = E.x + cs * O.x - sn * O.y;
    float Fy = E.y + cs * O.y + sn * O.x;
    float p = Fx * Fx + Fy * Fy;
    if (MODE == 0) {
      sm.S0[k] = fminf(p, 1.0e6f);
    } else if (MODE == 1) {
      sm.S1[k] = fminf(sm.S0[k], p);
    } else if (MODE == 2) {
      sm.S2[k] = fminf(sm.S1[k], p);
    } else {
      float m = fminf(sm.S2[k], p);
      m = fmaxf(m, 1.0e-10f);
      outp[(size_t)k * 8] = 10.0f * log10f(m);
    }
  }
}

__global__ __launch_bounds__(THREADS) void spec_kernel(const float* __restrict__ x,
                                                       float* __restrict__ out) {
  __shared__ Smem sm;
  const int b = blockIdx.x;
  const float* xb = x + (size_t)b * BUF;
  for (int i = threadIdx.x; i < BUF; i += THREADS) sm.xs[i] = xb[i];
  // frame_power starts with __syncthreads(), covering xs writes.

  float* outb = out + (size_t)b * NBANDS * 8;

  frame_power<0>(sm, 0, 1024, nullptr);                 // lvl0, frame 0
  for (int i1 = 0; i1 < 2; ++i1) {
    frame_power<1>(sm, 1, 512 * (i1 + 1), nullptr);     // lvl1
    for (int i2 = 2 * i1; i2 < 2 * i1 + 2; ++i2) {
      frame_power<2>(sm, 2, 256 * (i2 + 1), nullptr);   // lvl2
      for (int i3 = 2 * i2; i3 < 2 * i2 + 2; ++i3) {
        frame_power<3>(sm, 3, 128 * (i3 + 1), outb + i3); // lvl3 leaf -> t=i3
      }
    }
  }
}

extern "C" void kernel_launch(void* const* d_in, const int* in_sizes, int n_in,
                              void* d_out, int out_size, void* d_ws, size_t ws_size,
                              hipStream_t stream) {
  const float* x = (const float*)d_in[0];
  float* out = (float*)d_out;
  const int B = in_sizes[0] / BUF;
  hipLaunchKernelGGL(spec_kernel, dim3(B), dim3(THREADS), 0, stream, x, out);
}

// Round 2
// 322.672 us; speedup vs baseline: 1.0681x; 1.0681x over previous
//
#include <hip/hip_runtime.h>
#include <math.h>

#define NBANDS 2049
#define NF 4096      // real frame size
#define NC 2048      // complex FFT size (rfft via packed complex)
#define BUF 1024     // input samples per batch row
#define THREADS 512

// exp(-pi*i/2048)
#define C1 0.99999882345170187f
#define S1 0.00153398018628476f

struct Smem {
  float  xs[BUF];        // 4 KB
  float2 zs[NC];         // 16 KB (in-place FFT buffer)
  float  S0[NBANDS];     // 8.2 KB
  float  S1v[NBANDS];
  float  S2[NBANDS];
  float2 T[1025];        // 8.2 KB twiddles: T[m] = exp(-2*pi*i*m/2048)
};                       // total ~53.3 KB -> 3 blocks/CU

__device__ __forceinline__ float2 cmul(float2 a, float2 b) {
  return make_float2(a.x * b.x - a.y * b.y, a.x * b.y + a.y * b.x);
}

// MODE: 0 -> S0=min(p,1e6); 1 -> S1=min(S0,p); 2 -> S2=min(S1,p); 3 -> out=dB(min(S2,p))
template <int LVL, int MODE>
__device__ void frame_power(Smem& sm, int off, float* outp) {
  const int tid = threadIdx.x;
  constexpr int M = NF >> LVL;             // window support length
  const int k0 = max(NF - off, NF - M);    // first nonzero sample of w*frame
  constexpr float ws = (float)(1 << LVL) * (0.5f / 1024.0f);
  const int xoff = NF - off;               // frame[k] = x[k - xoff] for k >= xoff

  __syncthreads();   // previous frame's readers done with zs
  // ---- pack windowed frame: z[n] = wf(2n) + i*wf(2n+1) ----
  for (int n = tid; n < NC; n += THREADS) {
    float re = 0.0f, im = 0.0f;
    int k = 2 * n;
    if (k >= k0) {
      float c;
      if (LVL == 0) {
        c = cospif((float)k * (1.0f / 2048.0f));
      } else {
        int m = (k << (LVL - 1)) & 2047;
        if (m > 1024) m = 2048 - m;
        c = sm.T[m].x;
      }
      re = ws * (1.0f - c) * sm.xs[k - xoff];
    }
    k = 2 * n + 1;
    if (k >= k0) {
      float c;
      if (LVL == 0) {
        c = cospif((float)k * (1.0f / 2048.0f));
      } else {
        int m = (k << (LVL - 1)) & 2047;
        if (m > 1024) m = 2048 - m;
        c = sm.T[m].x;
      }
      im = ws * (1.0f - c) * sm.xs[k - xoff];
    }
    sm.zs[n] = make_float2(re, im);
  }

  // ---- in-place DIF radix-2, 11 stages, output bit-reversed ----
  #pragma unroll
  for (int st = 0; st < 11; ++st) {
    const int span = 1024 >> st;
    __syncthreads();
    #pragma unroll
    for (int jj = 0; jj < 2; ++jj) {
      const int j = tid + jj * THREADS;
      const int pos = j & (span - 1);
      const int i0 = 2 * j - pos;
      const int i1 = i0 + span;
      float2 a = sm.zs[i0];
      float2 b = sm.zs[i1];
      float2 tw = sm.T[pos << st];
      float2 d = make_float2(a.x - b.x, a.y - b.y);
      sm.zs[i0] = make_float2(a.x + b.x, a.y + b.y);
      sm.zs[i1] = cmul(d, tw);
    }
  }
  __syncthreads();

  // ---- unpack rfft bins (bit-reversed reads) + power + min-chain ----
  for (int k = tid; k < NBANDS; k += THREADS) {
    const int k1 = k & (NC - 1);
    const int k2 = (NC - k) & (NC - 1);
    float2 Zk = sm.zs[__brev((unsigned)k1) >> 21];
    float2 Zm = sm.zs[__brev((unsigned)k2) >> 21];
    float2 Bc = make_float2(Zm.x, -Zm.y);           // conj(Z[N-k])
    float2 E = make_float2(0.5f * (Zk.x + Bc.x), 0.5f * (Zk.y + Bc.y));
    float2 O = make_float2(0.5f * (Zk.y - Bc.y), -0.5f * (Zk.x - Bc.x)); // -i/2*(Zk-Bc)
    // U = exp(-pi*i*k/2048)
    float2 Th = sm.T[k >> 1];
    float2 U = (k & 1) ? cmul(Th, make_float2(C1, -S1)) : Th;
    float Fx = E.x + U.x * O.x - U.y * O.y;
    float Fy = E.y + U.x * O.y + U.y * O.x;
    float p = Fx * Fx + Fy * Fy;
    if (MODE == 0) {
      sm.S0[k] = fminf(p, 1.0e6f);
    } else if (MODE == 1) {
      sm.S1v[k] = fminf(sm.S0[k], p);
    } else if (MODE == 2) {
      sm.S2[k] = fminf(sm.S1v[k], p);
    } else {
      float m = fminf(sm.S2[k], p);
      m = fmaxf(m, 1.0e-10f);
      outp[(size_t)k * 8] = 10.0f * log10f(m);
    }
  }
}

__global__ __launch_bounds__(THREADS) void spec_kernel(const float* __restrict__ x,
                                                       float* __restrict__ out) {
  __shared__ Smem sm;
  const int b = blockIdx.x;
  const float* xb = x + (size_t)b * BUF;
  for (int i = threadIdx.x; i < BUF; i += THREADS) sm.xs[i] = xb[i];
  // twiddle table: T[m] = exp(-2*pi*i*m/2048) = cos(pi*m/1024) - i*sin(pi*m/1024)
  for (int m = threadIdx.x; m <= 1024; m += THREADS) {
    float sn, cs;
    sincospif((float)m * (1.0f / 1024.0f), &sn, &cs);
    sm.T[m] = make_float2(cs, -sn);
  }
  // frame_power starts with __syncthreads(), covering xs/T writes.

  float* outb = out + (size_t)b * NBANDS * 8;

  frame_power<0, 0>(sm, 1024, nullptr);                    // lvl0, frame 0
  for (int i1 = 0; i1 < 2; ++i1) {
    frame_power<1, 1>(sm, 512 * (i1 + 1), nullptr);        // lvl1
    for (int i2 = 2 * i1; i2 < 2 * i1 + 2; ++i2) {
      frame_power<2, 2>(sm, 256 * (i2 + 1), nullptr);      // lvl2
      for (int i3 = 2 * i2; i3 < 2 * i2 + 2; ++i3) {
        frame_power<3, 3>(sm, 128 * (i3 + 1), outb + i3);  // lvl3 leaf -> t=i3
      }
    }
  }
}

extern "C" void kernel_launch(void* const* d_in, const int* in_sizes, int n_in,
                              void* d_out, int out_size, void* d_ws, size_t ws_size,
                              hipStream_t stream) {
  const float* x = (const float*)d_in[0];
  float* out = (float*)d_out;
  const int B = in_sizes[0] / BUF;
  hipLaunchKernelGGL(spec_kernel, dim3(B), dim3(THREADS), 0, stream, x, out);
}

// Round 3
// 144.545 us; speedup vs baseline: 2.3845x; 2.2323x over previous
//
#include <hip/hip_runtime.h>
#include <math.h>

#define NBANDS 2049
#define NF 4096      // real frame size
#define NC 2048      // complex FFT size (rfft via packed complex)
#define BUF 1024     // input samples per batch row
#define THREADS 512
#define R2 0.70710678118654752f

// LDS bank swizzle: bijective on [0,2048), keeps all FFT/unpack patterns <=2-way
__device__ __forceinline__ int SW(int i) { return i ^ (i >> 2) ^ (i >> 6); }

// position of frequency k after DIF stages [4,4,4,4,4,2]
__device__ __forceinline__ int posrev(int k) {
  return ((k & 3) << 9) | (((k >> 2) & 3) << 7) | (((k >> 4) & 3) << 5) |
         (((k >> 6) & 3) << 3) | (((k >> 8) & 3) << 1) | ((k >> 10) & 1);
}

struct Smem {
  float xs[BUF];     // 4 KB
  float zre[NC];     // 8 KB
  float zim[NC];     // 8 KB
};                   // 20.5 KB -> 3+ blocks/CU (LDS-wise)

struct State {
  float2 W[5];            // per-thread stage twiddles W_{4m}^{tid%m}
  float2 Ub;              // exp(-pi*i*tid/2048)
  float s0[5], s1[5], s2[5];  // running-min chain, band k = tid + it*512
  float o[4][5];          // staged output columns for current lvl1 subtree
};

__device__ __forceinline__ float2 cmul(float2 a, float2 b) {
  return make_float2(a.x * b.x - a.y * b.y, a.x * b.y + a.y * b.x);
}

template <int LM>   // log2(m), butterfly span m
__device__ __forceinline__ void radix4(Smem& sm, float2 W) {
  const int j = threadIdx.x;
  const int m = 1 << LM;
  const int base = ((j >> LM) << (LM + 2)) | (j & (m - 1));
  const int i0 = SW(base), i1 = SW(base + m), i2 = SW(base + 2 * m), i3 = SW(base + 3 * m);
  float ar = sm.zre[i0], ai = sm.zim[i0];
  float br = sm.zre[i1], bi = sm.zim[i1];
  float cr = sm.zre[i2], ci = sm.zim[i2];
  float dr = sm.zre[i3], di = sm.zim[i3];
  float t0r = ar + cr, t0i = ai + ci;
  float t1r = ar - cr, t1i = ai - ci;
  float t2r = br + dr, t2i = bi + di;
  float t3r = br - dr, t3i = bi - di;
  // y0 = t0 + t2 (no twiddle)
  sm.zre[i0] = t0r + t2r; sm.zim[i0] = t0i + t2i;
  float2 W2 = make_float2(W.x * W.x - W.y * W.y, 2.0f * W.x * W.y);
  float2 W3 = cmul(W, W2);
  // y1 = (t1 - i*t3) * W
  float y1r = t1r + t3i, y1i = t1i - t3r;
  sm.zre[i1] = y1r * W.x - y1i * W.y; sm.zim[i1] = y1r * W.y + y1i * W.x;
  // y2 = (t0 - t2) * W^2
  float y2r = t0r - t2r, y2i = t0i - t2i;
  sm.zre[i2] = y2r * W2.x - y2i * W2.y; sm.zim[i2] = y2r * W2.y + y2i * W2.x;
  // y3 = (t1 + i*t3) * W^3
  float y3r = t1r - t3i, y3i = t1i + t3r;
  sm.zre[i3] = y3r * W3.x - y3i * W3.y; sm.zim[i3] = y3r * W3.y + y3i * W3.x;
}

// MODE: 0 s0=min(p,1e6); 1 s1=min(s0,p); 2 s2=min(s1,p); 3 o[TCOL]=dB(min(s2,p))
template <int LVL, int MODE, int TCOL>
__device__ __forceinline__ void frame_power(Smem& sm, State& st, int off) {
  const int tid = threadIdx.x;
  constexpr int M = NF >> LVL;              // window support
  constexpr int s = 1 << LVL;
  constexpr float ws = (float)s * (0.5f / 1024.0f);
  const int k0 = max(NF - off, NF - M);     // first nonzero sample (even)
  const int xoff = NF - off;

  __syncthreads();                          // prior readers done with zre/zim
  #pragma unroll
  for (int it = 0; it < 4; ++it) {
    const int n = tid + it * THREADS;
    const int k = 2 * n;
    float re = 0.0f, im = 0.0f;
    if (k >= k0) {
      const float2 xv = *(const float2*)&sm.xs[k - xoff];
      const float c0 = cospif((float)(k * s) * (1.0f / 2048.0f));
      const float c1 = cospif((float)((k + 1) * s) * (1.0f / 2048.0f));
      re = ws * (1.0f - c0) * xv.x;
      im = ws * (1.0f - c1) * xv.y;
    }
    const int p = SW(n);
    sm.zre[p] = re;
    sm.zim[p] = im;
  }

  __syncthreads(); radix4<9>(sm, st.W[0]);
  __syncthreads(); radix4<7>(sm, st.W[1]);
  __syncthreads(); radix4<5>(sm, st.W[2]);
  __syncthreads(); radix4<3>(sm, st.W[3]);
  __syncthreads(); radix4<1>(sm, st.W[4]);
  __syncthreads();
  // final radix-2 on adjacent pairs (twiddle-free)
  #pragma unroll
  for (int jj = 0; jj < 2; ++jj) {
    const int i = 2 * (tid + jj * THREADS);
    const int p0 = SW(i), p1 = SW(i + 1);
    float ar = sm.zre[p0], ai = sm.zim[p0];
    float br = sm.zre[p1], bi = sm.zim[p1];
    sm.zre[p0] = ar + br; sm.zim[p0] = ai + bi;
    sm.zre[p1] = ar - br; sm.zim[p1] = ai - bi;
  }
  __syncthreads();

  // unpack rfft bins (digit-reversed positions) + power + min-chain
  #pragma unroll
  for (int it = 0; it < 5; ++it) {
    if (it < 4 || tid == 0) {
      const int k = tid + it * THREADS;
      const int k1 = k & (NC - 1);
      const int k2 = (NC - k) & (NC - 1);
      const int p1 = SW(posrev(k1));
      const int p2 = SW(posrev(k2));
      const float zkr = sm.zre[p1], zki = sm.zim[p1];
      const float zmr = sm.zre[p2], zmi = sm.zim[p2];
      const float Ex = 0.5f * (zkr + zmr), Ey = 0.5f * (zki - zmi);
      const float Ox = 0.5f * (zki + zmi), Oy = -0.5f * (zkr - zmr);
      // U = exp(-pi*i*k/2048) = Ub * exp(-i*pi*it/4)
      float2 U;
      if (it == 0)      U = st.Ub;
      else if (it == 1) U = cmul(st.Ub, make_float2(R2, -R2));
      else if (it == 2) U = make_float2(st.Ub.y, -st.Ub.x);
      else if (it == 3) U = cmul(st.Ub, make_float2(-R2, -R2));
      else              U = make_float2(-st.Ub.x, -st.Ub.y);   // k=2048 (tid 0)
      const float Fx = Ex + U.x * Ox - U.y * Oy;
      const float Fy = Ey + U.x * Oy + U.y * Ox;
      const float p = Fx * Fx + Fy * Fy;
      if (MODE == 0)      st.s0[it] = fminf(p, 1.0e6f);
      else if (MODE == 1) st.s1[it] = fminf(st.s0[it], p);
      else if (MODE == 2) st.s2[it] = fminf(st.s1[it], p);
      else {
        const float mn = fmaxf(fminf(st.s2[it], p), 1.0e-10f);
        st.o[TCOL][it] = 10.0f * log10f(mn);
      }
    }
  }
}

template <int T0>
__device__ __forceinline__ void store_cols(State& st, float* __restrict__ outb) {
  const int tid = threadIdx.x;
  #pragma unroll
  for (int it = 0; it < 5; ++it) {
    if (it < 4 || tid == 0) {
      const int band = tid + it * THREADS;
      float4 v = make_float4(st.o[0][it], st.o[1][it], st.o[2][it], st.o[3][it]);
      *(float4*)&outb[(size_t)band * 8 + T0] = v;
    }
  }
}

__global__ __launch_bounds__(THREADS) void spec_kernel(const float* __restrict__ x,
                                                       float* __restrict__ out) {
  __shared__ Smem sm;
  State st;
  const int tid = threadIdx.x;
  const int b = blockIdx.x;
  const float* xb = x + (size_t)b * BUF;
  #pragma unroll
  for (int i = tid; i < BUF; i += THREADS) sm.xs[i] = xb[i];
  {
    float sn, cs;
    sincospif((float)tid * (1.0f / 1024.0f), &sn, &cs);          st.W[0] = make_float2(cs, -sn);
    sincospif((float)(tid & 127) * (1.0f / 256.0f), &sn, &cs);   st.W[1] = make_float2(cs, -sn);
    sincospif((float)(tid & 31) * (1.0f / 64.0f), &sn, &cs);     st.W[2] = make_float2(cs, -sn);
    sincospif((float)(tid & 7) * (1.0f / 16.0f), &sn, &cs);      st.W[3] = make_float2(cs, -sn);
    st.W[4] = (tid & 1) ? make_float2(R2, -R2) : make_float2(1.0f, 0.0f);
    sincospif((float)tid * (1.0f / 2048.0f), &sn, &cs);          st.Ub = make_float2(cs, -sn);
  }
  float* outb = out + (size_t)b * (NBANDS * 8);

  // depth-first min-tree walk; off = chunk*(i+1) per level
  frame_power<0, 0, 0>(sm, st, 1024);
  frame_power<1, 1, 0>(sm, st, 512);
  frame_power<2, 2, 0>(sm, st, 256);
  frame_power<3, 3, 0>(sm, st, 128);
  frame_power<3, 3, 1>(sm, st, 256);
  frame_power<2, 2, 0>(sm, st, 512);
  frame_power<3, 3, 2>(sm, st, 384);
  frame_power<3, 3, 3>(sm, st, 512);
  store_cols<0>(st, outb);
  frame_power<1, 1, 0>(sm, st, 1024);
  frame_power<2, 2, 0>(sm, st, 768);
  frame_power<3, 3, 0>(sm, st, 640);
  frame_power<3, 3, 1>(sm, st, 768);
  frame_power<2, 2, 0>(sm, st, 1024);
  frame_power<3, 3, 2>(sm, st, 896);
  frame_power<3, 3, 3>(sm, st, 1024);
  store_cols<4>(st, outb);
}

extern "C" void kernel_launch(void* const* d_in, const int* in_sizes, int n_in,
                              void* d_out, int out_size, void* d_ws, size_t ws_size,
                              hipStream_t stream) {
  const float* x = (const float*)d_in[0];
  float* out = (float*)d_out;
  const int B = in_sizes[0] / BUF;
  hipLaunchKernelGGL(spec_kernel, dim3(B), dim3(THREADS), 0, stream, x, out);
}